// Round 1
// baseline (1119.225 us; speedup 1.0000x reference)
//
#include <hip/hip_runtime.h>
#include <hip/hip_bf16.h>
#include <math.h>

#define V     10000
#define EMB   512
#define H     1024
#define H3    3072
#define SEQ   64
#define MAXLEN 64

__device__ __forceinline__ float sigmoidf_(float x) { return 1.0f / (1.0f + expf(-x)); }

// ---------------- init: load enc_state into ping-pong h buffers ----------------
// h0buf[0] <- enc_state[0:1024]  (layer0 init, read by phase 0 which reads buf index 0)
// h1buf[1] <- enc_state[1024:2048] (layer1 init, read by phase 1 which reads buf index 1)
__global__ void init_h_kernel(const float* __restrict__ enc_state,
                              float* __restrict__ h0buf, float* __restrict__ h1buf) {
    int i = blockIdx.x * blockDim.x + threadIdx.x;
    if (i < H)            h0buf[i] = enc_state[i];
    else if (i < 2 * H)   h1buf[H + (i - H)] = enc_state[i];
}

// ---------------- embedding gather for encoder + decoder inputs ----------------
__global__ void embed_kernel(const int* __restrict__ cs, const int* __restrict__ sos,
                             const int* __restrict__ tgt, const float* __restrict__ emb,
                             float* __restrict__ e_enc, float* __restrict__ e_dec) {
    int t = blockIdx.x;  // 0..127
    int id;
    float* dst;
    if (t < SEQ) { id = cs[t]; dst = e_enc + (size_t)t * EMB; }
    else         { int td = t - SEQ; id = (td == 0) ? sos[0] : tgt[td - 1]; dst = e_dec + (size_t)td * EMB; }
    const float4* src4 = (const float4*)(emb + (size_t)id * EMB);
    float4* dst4 = (float4*)dst;
    dst4[threadIdx.x] = src4[threadIdx.x];  // 128 threads x float4 = 512 floats
}

// ---------------- gi0 = e @ Wih0.T + bih0 for all 64 timesteps ----------------
// one wave per output row (3072 rows); lane holds 8 weight elems, loops 64 timesteps
__global__ __launch_bounds__(256) void gi0_kernel(const float* __restrict__ e,
                                                  const float* __restrict__ W,
                                                  const float* __restrict__ bih,
                                                  float* __restrict__ gi) {
    int wave = (blockIdx.x * 256 + threadIdx.x) >> 6;
    int lane = threadIdx.x & 63;
    if (wave >= H3) return;
    int row = wave;
    float4 w0 = *(const float4*)(W + (size_t)row * EMB + lane * 8);
    float4 w1 = *(const float4*)(W + (size_t)row * EMB + lane * 8 + 4);
    float bb = bih[row];
    for (int t = 0; t < SEQ; ++t) {
        float4 x0 = *(const float4*)(e + (size_t)t * EMB + lane * 8);
        float4 x1 = *(const float4*)(e + (size_t)t * EMB + lane * 8 + 4);
        float s = w0.x * x0.x + w0.y * x0.y + w0.z * x0.z + w0.w * x0.w
                + w1.x * x1.x + w1.y * x1.y + w1.z * x1.z + w1.w * x1.w;
        #pragma unroll
        for (int m = 1; m < 64; m <<= 1) s += __shfl_xor(s, m);
        if (lane == 0) gi[(size_t)t * H3 + row] = s + bb;
    }
}

// ---------------- phase kernel: part A = layer0 step tA; part B = layer1 step tB ----------------
// A: h0_new[j] = GRUcell(gi=giA[.][j] precomputed, h=h0r, Whh=WhhA)
// B: h1_new[j] = GRUcell(x=h0r (layer0 out of step tB), h=h1r, Wih=WihB, Whh=WhhB)
__global__ __launch_bounds__(256) void phase_kernel(
    const float* __restrict__ giA, const float* __restrict__ WhhA, const float* __restrict__ bhhA,
    const float* __restrict__ h0r, float* __restrict__ h0w, float* __restrict__ statesA, int hasA,
    const float* __restrict__ WihB, const float* __restrict__ bihB,
    const float* __restrict__ WhhB, const float* __restrict__ bhhB,
    const float* __restrict__ h1r, float* __restrict__ h1w, float* __restrict__ statesB, int hasB) {
    int wave = (blockIdx.x * 256 + threadIdx.x) >> 6;
    int lane = threadIdx.x & 63;
    if (wave < H) {
        if (!hasA) return;
        int j = wave;
        const float* w0 = WhhA + (size_t)j * H;
        const float* w1 = WhhA + (size_t)(j + H) * H;
        const float* w2 = WhhA + (size_t)(j + 2 * H) * H;
        float s0 = 0.f, s1 = 0.f, s2 = 0.f;
        #pragma unroll
        for (int k = lane * 4; k < H; k += 256) {
            float4 hv = *(const float4*)(h0r + k);
            float4 a = *(const float4*)(w0 + k);
            float4 b = *(const float4*)(w1 + k);
            float4 c = *(const float4*)(w2 + k);
            s0 += a.x * hv.x + a.y * hv.y + a.z * hv.z + a.w * hv.w;
            s1 += b.x * hv.x + b.y * hv.y + b.z * hv.z + b.w * hv.w;
            s2 += c.x * hv.x + c.y * hv.y + c.z * hv.z + c.w * hv.w;
        }
        #pragma unroll
        for (int m = 1; m < 64; m <<= 1) {
            s0 += __shfl_xor(s0, m);
            s1 += __shfl_xor(s1, m);
            s2 += __shfl_xor(s2, m);
        }
        if (lane == 0) {
            float r = sigmoidf_(giA[j] + s0 + bhhA[j]);
            float z = sigmoidf_(giA[H + j] + s1 + bhhA[H + j]);
            float n = tanhf(giA[2 * H + j] + r * (s2 + bhhA[2 * H + j]));
            float hp = h0r[j];
            float hn = (1.f - z) * n + z * hp;
            h0w[j] = hn;
            if (statesA) statesA[j] = hn;
        }
    } else {
        if (!hasB) return;
        int j = wave - H;
        const float* wi0 = WihB + (size_t)j * H;
        const float* wi1 = WihB + (size_t)(j + H) * H;
        const float* wi2 = WihB + (size_t)(j + 2 * H) * H;
        const float* wh0 = WhhB + (size_t)j * H;
        const float* wh1 = WhhB + (size_t)(j + H) * H;
        const float* wh2 = WhhB + (size_t)(j + 2 * H) * H;
        float si0 = 0.f, si1 = 0.f, si2 = 0.f, sh0 = 0.f, sh1 = 0.f, sh2 = 0.f;
        #pragma unroll
        for (int k = lane * 4; k < H; k += 256) {
            float4 xv = *(const float4*)(h0r + k);   // layer0 output at step tB
            float4 hv = *(const float4*)(h1r + k);
            float4 a = *(const float4*)(wi0 + k);
            float4 b = *(const float4*)(wi1 + k);
            float4 c = *(const float4*)(wi2 + k);
            si0 += a.x * xv.x + a.y * xv.y + a.z * xv.z + a.w * xv.w;
            si1 += b.x * xv.x + b.y * xv.y + b.z * xv.z + b.w * xv.w;
            si2 += c.x * xv.x + c.y * xv.y + c.z * xv.z + c.w * xv.w;
            float4 d = *(const float4*)(wh0 + k);
            float4 e = *(const float4*)(wh1 + k);
            float4 f = *(const float4*)(wh2 + k);
            sh0 += d.x * hv.x + d.y * hv.y + d.z * hv.z + d.w * hv.w;
            sh1 += e.x * hv.x + e.y * hv.y + e.z * hv.z + e.w * hv.w;
            sh2 += f.x * hv.x + f.y * hv.y + f.z * hv.z + f.w * hv.w;
        }
        #pragma unroll
        for (int m = 1; m < 64; m <<= 1) {
            si0 += __shfl_xor(si0, m);
            si1 += __shfl_xor(si1, m);
            si2 += __shfl_xor(si2, m);
            sh0 += __shfl_xor(sh0, m);
            sh1 += __shfl_xor(sh1, m);
            sh2 += __shfl_xor(sh2, m);
        }
        if (lane == 0) {
            float r = sigmoidf_(si0 + bihB[j] + sh0 + bhhB[j]);
            float z = sigmoidf_(si1 + bihB[H + j] + sh1 + bhhB[H + j]);
            float n = tanhf(si2 + bihB[2 * H + j] + r * (sh2 + bhhB[2 * H + j]));
            float hp = h1r[j];
            float hn = (1.f - z) * n + z * hp;
            h1w[j] = hn;
            if (statesB) statesB[j] = hn;
        }
    }
}

// ---------------- final scores GEMM: out[t][r] = h1dec[t] . out_W[r] + out_b[r] ----------------
// M=64 (t), N=10000 (r), K=1024. 64x64 tile, K-tile 64.
#define SN 64
#define SK 64
__global__ __launch_bounds__(256) void scores_kernel(const float* __restrict__ states,
                                                     const float* __restrict__ W,
                                                     const float* __restrict__ bias,
                                                     float* __restrict__ out) {
    __shared__ float As[SK][64 + 1];
    __shared__ float Bs[SK][SN + 1];
    int n0 = blockIdx.x * SN;
    int tid = threadIdx.x;
    int tn = tid & 15, tm = tid >> 4;
    float acc[4][4] = {};
    for (int k0 = 0; k0 < H; k0 += SK) {
        for (int i = tid; i < 64 * (SK / 4); i += 256) {
            int m = i >> 4;
            int kq = i & 15;
            float4 v = *(const float4*)(states + (size_t)m * 2048 + H + k0 + kq * 4);
            As[kq * 4 + 0][m] = v.x; As[kq * 4 + 1][m] = v.y;
            As[kq * 4 + 2][m] = v.z; As[kq * 4 + 3][m] = v.w;
        }
        for (int i = tid; i < SN * (SK / 4); i += 256) {
            int n = i >> 4;
            int kq = i & 15;
            int r = n0 + n;
            float4 v = make_float4(0.f, 0.f, 0.f, 0.f);
            if (r < V) v = *(const float4*)(W + (size_t)r * H + k0 + kq * 4);
            Bs[kq * 4 + 0][n] = v.x; Bs[kq * 4 + 1][n] = v.y;
            Bs[kq * 4 + 2][n] = v.z; Bs[kq * 4 + 3][n] = v.w;
        }
        __syncthreads();
        #pragma unroll 8
        for (int k = 0; k < SK; ++k) {
            float a[4], b[4];
            #pragma unroll
            for (int i = 0; i < 4; ++i) a[i] = As[k][tm * 4 + i];
            #pragma unroll
            for (int j = 0; j < 4; ++j) b[j] = Bs[k][tn * 4 + j];
            #pragma unroll
            for (int i = 0; i < 4; ++i)
                #pragma unroll
                for (int j = 0; j < 4; ++j) acc[i][j] += a[i] * b[j];
        }
        __syncthreads();
    }
    #pragma unroll
    for (int i = 0; i < 4; ++i) {
        int m = tm * 4 + i;
        #pragma unroll
        for (int j = 0; j < 4; ++j) {
            int r = n0 + tn * 4 + j;
            if (r < V) out[(size_t)m * V + r] = acc[i][j] + bias[r];
        }
    }
}

extern "C" void kernel_launch(void* const* d_in, const int* in_sizes, int n_in,
                              void* d_out, int out_size, void* d_ws, size_t ws_size,
                              hipStream_t stream) {
    const int*   char_seq  = (const int*)d_in[0];
    const float* enc_state = (const float*)d_in[1];
    const int*   sos       = (const int*)d_in[2];
    const int*   tgt       = (const int*)d_in[5];
    const float* emb       = (const float*)d_in[6];
    const float* enc_Wih0  = (const float*)d_in[7];
    const float* enc_Whh0  = (const float*)d_in[8];
    const float* enc_bih0  = (const float*)d_in[9];
    const float* enc_bhh0  = (const float*)d_in[10];
    const float* enc_Wih1  = (const float*)d_in[11];
    const float* enc_Whh1  = (const float*)d_in[12];
    const float* enc_bih1  = (const float*)d_in[13];
    const float* enc_bhh1  = (const float*)d_in[14];
    const float* dec_Wih0  = (const float*)d_in[15];
    const float* dec_Whh0  = (const float*)d_in[16];
    const float* dec_bih0  = (const float*)d_in[17];
    const float* dec_bhh0  = (const float*)d_in[18];
    const float* dec_Wih1  = (const float*)d_in[19];
    const float* dec_Whh1  = (const float*)d_in[20];
    const float* dec_bih1  = (const float*)d_in[21];
    const float* dec_bhh1  = (const float*)d_in[22];
    const float* out_W     = (const float*)d_in[23];
    const float* out_b     = (const float*)d_in[24];

    float* ws = (float*)d_ws;
    float* e_enc   = ws;                       // 64*512
    float* e_dec   = e_enc + SEQ * EMB;        // 64*512
    float* gi_enc0 = e_dec + SEQ * EMB;        // 64*3072
    float* gi_dec0 = gi_enc0 + SEQ * H3;       // 64*3072
    float* h0buf   = gi_dec0 + SEQ * H3;       // 2*1024 ping-pong
    float* h1buf   = h0buf + 2 * H;            // 2*1024 ping-pong

    float* scores = (float*)d_out;             // 64*10000
    float* states = scores + SEQ * V;          // 64*2048

    init_h_kernel<<<8, 256, 0, stream>>>(enc_state, h0buf, h1buf);
    embed_kernel<<<128, 128, 0, stream>>>(char_seq, sos, tgt, emb, e_enc, e_dec);
    gi0_kernel<<<H3 / 4, 256, 0, stream>>>(e_enc, enc_Wih0, enc_bih0, gi_enc0);
    gi0_kernel<<<H3 / 4, 256, 0, stream>>>(e_dec, dec_Wih0, dec_bih0, gi_dec0);

    // 129 pipelined phases: phase p does layer0 of step t_A(p) and layer1 of step t_B(p)=t_A(p)-1
    for (int p = 0; p <= 128; ++p) {
        int hasA = (p <= 127);
        int hasB = (p >= 1);
        const float* giA = nullptr; const float* WhhA = nullptr; const float* bhhA = nullptr;
        float* statesA = nullptr;
        if (hasA) {
            if (p < 64) { giA = gi_enc0 + (size_t)p * H3; WhhA = enc_Whh0; bhhA = enc_bhh0; }
            else {
                int t = p - 64;
                giA = gi_dec0 + (size_t)t * H3; WhhA = dec_Whh0; bhhA = dec_bhh0;
                statesA = states + (size_t)t * 2048;
            }
        }
        const float *WihB = nullptr, *bihB = nullptr, *WhhB = nullptr, *bhhB = nullptr;
        float* statesB = nullptr;
        if (hasB) {
            if (p <= 64) { WihB = enc_Wih1; bihB = enc_bih1; WhhB = enc_Whh1; bhhB = enc_bhh1; }
            else {
                int t = p - 65;
                WihB = dec_Wih1; bihB = dec_bih1; WhhB = dec_Whh1; bhhB = dec_bhh1;
                statesB = states + (size_t)t * 2048 + H;
            }
        }
        float* h0r = h0buf + (p & 1) * H;
        float* h0w = h0buf + ((p + 1) & 1) * H;
        float* h1r = h1buf + (p & 1) * H;
        float* h1w = h1buf + ((p + 1) & 1) * H;
        phase_kernel<<<512, 256, 0, stream>>>(giA, WhhA, bhhA, h0r, h0w, statesA, hasA,
                                              WihB, bihB, WhhB, bhhB, h1r, h1w, statesB, hasB);
    }

    scores_kernel<<<(V + SN - 1) / SN, 256, 0, stream>>>(states, out_W, out_b, scores);
}

// Round 2
// 1029.746 us; speedup vs baseline: 1.0869x; 1.0869x over previous
//
#include <hip/hip_runtime.h>
#include <hip/hip_bf16.h>
#include <math.h>

#define V     10000
#define EMB   512
#define H     1024
#define H3    3072
#define SEQ   64
#define NPAD  10048   // 157*64, padded N for score partials

__device__ __forceinline__ float sigmoidf_(float x) { return 1.0f / (1.0f + expf(-x)); }

// ---------------- init: load enc_state into ping-pong h buffers ----------------
__global__ void init_h_kernel(const float* __restrict__ enc_state,
                              float* __restrict__ h0buf, float* __restrict__ h1buf) {
    int i = blockIdx.x * blockDim.x + threadIdx.x;
    if (i < H)            h0buf[i] = enc_state[i];
    else if (i < 2 * H)   h1buf[H + (i - H)] = enc_state[i];
}

// ---------------- embedding gather ----------------
__global__ void embed_kernel(const int* __restrict__ cs, const int* __restrict__ sos,
                             const int* __restrict__ tgt, const float* __restrict__ emb,
                             float* __restrict__ e_enc, float* __restrict__ e_dec) {
    int t = blockIdx.x;  // 0..127
    int id;
    float* dst;
    if (t < SEQ) { id = cs[t]; dst = e_enc + (size_t)t * EMB; }
    else         { int td = t - SEQ; id = (td == 0) ? sos[0] : tgt[td - 1]; dst = e_dec + (size_t)td * EMB; }
    const float4* src4 = (const float4*)(emb + (size_t)id * EMB);
    float4* dst4 = (float4*)dst;
    dst4[threadIdx.x] = src4[threadIdx.x];
}

// ---------------- gi0 = e @ Wih0.T + bih0 for all 64 timesteps ----------------
__global__ __launch_bounds__(256) void gi0_kernel(const float* __restrict__ e,
                                                  const float* __restrict__ W,
                                                  const float* __restrict__ bih,
                                                  float* __restrict__ gi) {
    int wave = (blockIdx.x * 256 + threadIdx.x) >> 6;
    int lane = threadIdx.x & 63;
    if (wave >= H3) return;
    int row = wave;
    float4 w0 = *(const float4*)(W + (size_t)row * EMB + lane * 8);
    float4 w1 = *(const float4*)(W + (size_t)row * EMB + lane * 8 + 4);
    float bb = bih[row];
    for (int t = 0; t < SEQ; ++t) {
        float4 x0 = *(const float4*)(e + (size_t)t * EMB + lane * 8);
        float4 x1 = *(const float4*)(e + (size_t)t * EMB + lane * 8 + 4);
        float s = w0.x * x0.x + w0.y * x0.y + w0.z * x0.z + w0.w * x0.w
                + w1.x * x1.x + w1.y * x1.y + w1.z * x1.z + w1.w * x1.w;
        #pragma unroll
        for (int m = 1; m < 64; m <<= 1) s += __shfl_xor(s, m);
        if (lane == 0) gi[(size_t)t * H3 + row] = s + bb;
    }
}

// ---------------- phase kernel: one wave = one K=1024 row-dot ----------------
// Blocks 0..511   (A): block b owns j = {2b, 2b+1} of layer0; wave w -> (t=w/3, g=w%3)
// Blocks 512..1535(B): block owns j = b-512 of layer1; waves 0-2 ih gates, 3-5 hh gates
__global__ __launch_bounds__(384) void phase_kernel(
    const float* __restrict__ giA, const float* __restrict__ WhhA, const float* __restrict__ bhhA,
    const float* __restrict__ h0r, float* __restrict__ h0w, float* __restrict__ statesA, int hasA,
    const float* __restrict__ WihB, const float* __restrict__ bihB,
    const float* __restrict__ WhhB, const float* __restrict__ bhhB,
    const float* __restrict__ h1r, float* __restrict__ h1w, float* __restrict__ statesB, int hasB) {
    __shared__ float sred[8];
    int bid = blockIdx.x;
    int tid = threadIdx.x;
    int w = tid >> 6, lane = tid & 63;
    if (bid < 512) {
        if (!hasA) return;
        int tt = w / 3, g = w - tt * 3;
        int j = bid * 2 + tt;
        const float* wrow = WhhA + (size_t)(g * H + j) * H;
        float s = 0.f;
        #pragma unroll
        for (int i = 0; i < 4; ++i) {
            int k = lane * 4 + i * 256;
            float4 wv = *(const float4*)(wrow + k);
            float4 xv = *(const float4*)(h0r + k);
            s += wv.x * xv.x + wv.y * xv.y + wv.z * xv.z + wv.w * xv.w;
        }
        #pragma unroll
        for (int m = 1; m < 64; m <<= 1) s += __shfl_xor(s, m);
        if (lane == 0) sred[w] = s;
        __syncthreads();
        if (tid < 2) {
            int jj = bid * 2 + tid;
            float s0 = sred[tid * 3], s1 = sred[tid * 3 + 1], s2 = sred[tid * 3 + 2];
            float r = sigmoidf_(giA[jj] + s0 + bhhA[jj]);
            float z = sigmoidf_(giA[H + jj] + s1 + bhhA[H + jj]);
            float n = tanhf(giA[2 * H + jj] + r * (s2 + bhhA[2 * H + jj]));
            float hn = (1.f - z) * n + z * h0r[jj];
            h0w[jj] = hn;
            if (statesA) statesA[jj] = hn;
        }
    } else {
        if (!hasB) return;
        int j = bid - 512;
        int hh = (w >= 3);
        int g = w - hh * 3;
        const float* wrow = (hh ? WhhB : WihB) + (size_t)(g * H + j) * H;
        const float* x = hh ? h1r : h0r;
        float s = 0.f;
        #pragma unroll
        for (int i = 0; i < 4; ++i) {
            int k = lane * 4 + i * 256;
            float4 wv = *(const float4*)(wrow + k);
            float4 xv = *(const float4*)(x + k);
            s += wv.x * xv.x + wv.y * xv.y + wv.z * xv.z + wv.w * xv.w;
        }
        #pragma unroll
        for (int m = 1; m < 64; m <<= 1) s += __shfl_xor(s, m);
        if (lane == 0) sred[w] = s;
        __syncthreads();
        if (tid == 0) {
            float r = sigmoidf_(sred[0] + bihB[j] + sred[3] + bhhB[j]);
            float z = sigmoidf_(sred[1] + bihB[H + j] + sred[4] + bhhB[H + j]);
            float n = tanhf(sred[2] + bihB[2 * H + j] + r * (sred[5] + bhhB[2 * H + j]));
            float hn = (1.f - z) * n + z * h1r[j];
            h1w[j] = hn;
            if (statesB) statesB[j] = hn;
        }
    }
}

// ---------------- scores GEMM, split-K: partial[kc] = states[:,H:] @ W.T over K-chunk ----------------
#define SN 64
#define SK 64
__global__ __launch_bounds__(256) void scores_kernel(const float* __restrict__ states,
                                                     const float* __restrict__ W,
                                                     const float* __restrict__ bias,
                                                     float* __restrict__ dst, int kc_count) {
    __shared__ float As[SK][64 + 1];
    __shared__ float Bs[SK][SN + 1];
    int n0 = blockIdx.x * SN;
    int kc = blockIdx.y;
    int klen = H / kc_count;
    int kbeg = kc * klen;
    int tid = threadIdx.x;
    int tn = tid & 15, tm = tid >> 4;
    float acc[4][4] = {};
    for (int k0 = kbeg; k0 < kbeg + klen; k0 += SK) {
        for (int i = tid; i < 64 * (SK / 4); i += 256) {
            int m = i >> 4;
            int kq = i & 15;
            float4 v = *(const float4*)(states + (size_t)m * 2048 + H + k0 + kq * 4);
            As[kq * 4 + 0][m] = v.x; As[kq * 4 + 1][m] = v.y;
            As[kq * 4 + 2][m] = v.z; As[kq * 4 + 3][m] = v.w;
        }
        for (int i = tid; i < SN * (SK / 4); i += 256) {
            int n = i >> 4;
            int kq = i & 15;
            int r = n0 + n;
            float4 v = make_float4(0.f, 0.f, 0.f, 0.f);
            if (r < V) v = *(const float4*)(W + (size_t)r * H + k0 + kq * 4);
            Bs[kq * 4 + 0][n] = v.x; Bs[kq * 4 + 1][n] = v.y;
            Bs[kq * 4 + 2][n] = v.z; Bs[kq * 4 + 3][n] = v.w;
        }
        __syncthreads();
        #pragma unroll 8
        for (int k = 0; k < SK; ++k) {
            float a[4], b[4];
            #pragma unroll
            for (int i = 0; i < 4; ++i) a[i] = As[k][tm * 4 + i];
            #pragma unroll
            for (int j = 0; j < 4; ++j) b[j] = Bs[k][tn * 4 + j];
            #pragma unroll
            for (int i = 0; i < 4; ++i)
                #pragma unroll
                for (int j = 0; j < 4; ++j) acc[i][j] += a[i] * b[j];
        }
        __syncthreads();
    }
    if (kc_count == 1) {
        #pragma unroll
        for (int i = 0; i < 4; ++i) {
            int m = tm * 4 + i;
            #pragma unroll
            for (int j = 0; j < 4; ++j) {
                int r = n0 + tn * 4 + j;
                if (r < V) dst[(size_t)m * V + r] = acc[i][j] + bias[r];
            }
        }
    } else {
        #pragma unroll
        for (int i = 0; i < 4; ++i) {
            int m = tm * 4 + i;
            #pragma unroll
            for (int j = 0; j < 4; ++j) {
                int r = n0 + tn * 4 + j;   // r < NPAD always
                dst[(size_t)(kc * 64 + m) * NPAD + r] = acc[i][j];
            }
        }
    }
}

__global__ __launch_bounds__(256) void reduce_scores_kernel(const float* __restrict__ part,
                                                            const float* __restrict__ bias,
                                                            float* __restrict__ out, int kc_count) {
    int e = blockIdx.x * 256 + threadIdx.x;
    if (e >= 64 * V) return;
    int m = e / V, r = e - m * V;
    float s = bias[r];
    for (int kc = 0; kc < kc_count; ++kc)
        s += part[(size_t)(kc * 64 + m) * NPAD + r];
    out[(size_t)m * V + r] = s;
}

extern "C" void kernel_launch(void* const* d_in, const int* in_sizes, int n_in,
                              void* d_out, int out_size, void* d_ws, size_t ws_size,
                              hipStream_t stream) {
    const int*   char_seq  = (const int*)d_in[0];
    const float* enc_state = (const float*)d_in[1];
    const int*   sos       = (const int*)d_in[2];
    const int*   tgt       = (const int*)d_in[5];
    const float* emb       = (const float*)d_in[6];
    const float* enc_Wih0  = (const float*)d_in[7];
    const float* enc_Whh0  = (const float*)d_in[8];
    const float* enc_bih0  = (const float*)d_in[9];
    const float* enc_bhh0  = (const float*)d_in[10];
    const float* enc_Wih1  = (const float*)d_in[11];
    const float* enc_Whh1  = (const float*)d_in[12];
    const float* enc_bih1  = (const float*)d_in[13];
    const float* enc_bhh1  = (const float*)d_in[14];
    const float* dec_Wih0  = (const float*)d_in[15];
    const float* dec_Whh0  = (const float*)d_in[16];
    const float* dec_bih0  = (const float*)d_in[17];
    const float* dec_bhh0  = (const float*)d_in[18];
    const float* dec_Wih1  = (const float*)d_in[19];
    const float* dec_Whh1  = (const float*)d_in[20];
    const float* dec_bih1  = (const float*)d_in[21];
    const float* dec_bhh1  = (const float*)d_in[22];
    const float* out_W     = (const float*)d_in[23];
    const float* out_b     = (const float*)d_in[24];

    float* ws = (float*)d_ws;
    float* e_enc   = ws;                       // 64*512
    float* e_dec   = e_enc + SEQ * EMB;        // 64*512
    float* gi_enc0 = e_dec + SEQ * EMB;        // 64*3072
    float* gi_dec0 = gi_enc0 + SEQ * H3;       // 64*3072
    float* h0buf   = gi_dec0 + SEQ * H3;       // 2*1024 ping-pong
    float* h1buf   = h0buf + 2 * H;            // 2*1024 ping-pong
    float* partials = h1buf + 2 * H;           // KC*64*NPAD

    size_t base_floats = (size_t)(partials - ws);
    int KC = 1;
    if ((base_floats + (size_t)4 * 64 * NPAD) * 4 <= ws_size) KC = 4;
    else if ((base_floats + (size_t)2 * 64 * NPAD) * 4 <= ws_size) KC = 2;

    float* scores = (float*)d_out;             // 64*10000
    float* states = scores + SEQ * V;          // 64*2048

    init_h_kernel<<<8, 256, 0, stream>>>(enc_state, h0buf, h1buf);
    embed_kernel<<<128, 128, 0, stream>>>(char_seq, sos, tgt, emb, e_enc, e_dec);
    gi0_kernel<<<H3 / 4, 256, 0, stream>>>(e_enc, enc_Wih0, enc_bih0, gi_enc0);
    gi0_kernel<<<H3 / 4, 256, 0, stream>>>(e_dec, dec_Wih0, dec_bih0, gi_dec0);

    for (int p = 0; p <= 128; ++p) {
        int hasA = (p <= 127);
        int hasB = (p >= 1);
        const float* giA = nullptr; const float* WhhA = nullptr; const float* bhhA = nullptr;
        float* statesA = nullptr;
        if (hasA) {
            if (p < 64) { giA = gi_enc0 + (size_t)p * H3; WhhA = enc_Whh0; bhhA = enc_bhh0; }
            else {
                int t = p - 64;
                giA = gi_dec0 + (size_t)t * H3; WhhA = dec_Whh0; bhhA = dec_bhh0;
                statesA = states + (size_t)t * 2048;
            }
        }
        const float *WihB = nullptr, *bihB = nullptr, *WhhB = nullptr, *bhhB = nullptr;
        float* statesB = nullptr;
        if (hasB) {
            if (p <= 64) { WihB = enc_Wih1; bihB = enc_bih1; WhhB = enc_Whh1; bhhB = enc_bhh1; }
            else {
                int t = p - 65;
                WihB = dec_Wih1; bihB = dec_bih1; WhhB = dec_Whh1; bhhB = dec_bhh1;
                statesB = states + (size_t)t * 2048 + H;
            }
        }
        float* h0r = h0buf + (p & 1) * H;
        float* h0w = h0buf + ((p + 1) & 1) * H;
        float* h1r = h1buf + (p & 1) * H;
        float* h1w = h1buf + ((p + 1) & 1) * H;
        phase_kernel<<<1536, 384, 0, stream>>>(giA, WhhA, bhhA, h0r, h0w, statesA, hasA,
                                               WihB, bihB, WhhB, bhhB, h1r, h1w, statesB, hasB);
    }

    if (KC == 1) {
        scores_kernel<<<dim3((V + SN - 1) / SN, 1), 256, 0, stream>>>(states, out_W, out_b, scores, 1);
    } else {
        scores_kernel<<<dim3((V + SN - 1) / SN, KC), 256, 0, stream>>>(states, out_W, out_b, partials, KC);
        reduce_scores_kernel<<<(64 * V + 255) / 256, 256, 0, stream>>>(partials, out_b, scores, KC);
    }
}

// Round 3
// 715.671 us; speedup vs baseline: 1.5639x; 1.4389x over previous
//
#include <hip/hip_runtime.h>
#include <hip/hip_bf16.h>
#include <math.h>

#define V     10000
#define EMB   512
#define H     1024
#define H3    3072
#define SEQ   64
#define NPAD  10048   // 157*64, padded N for score partials

typedef __attribute__((ext_vector_type(8))) unsigned short us8;

__device__ __forceinline__ float sigmoidf_(float x) { return 1.0f / (1.0f + expf(-x)); }
__device__ __forceinline__ float bf2f(unsigned short u) { return __uint_as_float(((unsigned)u) << 16); }
__device__ __forceinline__ unsigned short f2bf_rne(float f) {
    unsigned u = __float_as_uint(f);
    unsigned r = u + 0x7FFF + ((u >> 16) & 1);
    return (unsigned short)(r >> 16);
}

// ---------------- f32 -> bf16 weight conversion (8 elems/thread) ----------------
__global__ __launch_bounds__(256) void f2bf_kernel(const float* __restrict__ src,
                                                   unsigned short* __restrict__ dst, int n) {
    int i = (blockIdx.x * 256 + threadIdx.x) * 8;
    if (i >= n) return;
    float4 a = *(const float4*)(src + i);
    float4 b = *(const float4*)(src + i + 4);
    us8 o;
    o[0] = f2bf_rne(a.x); o[1] = f2bf_rne(a.y); o[2] = f2bf_rne(a.z); o[3] = f2bf_rne(a.w);
    o[4] = f2bf_rne(b.x); o[5] = f2bf_rne(b.y); o[6] = f2bf_rne(b.z); o[7] = f2bf_rne(b.w);
    *(us8*)(dst + i) = o;
}

// ---------------- init: load enc_state into ping-pong h buffers ----------------
__global__ void init_h_kernel(const float* __restrict__ enc_state,
                              float* __restrict__ h0buf, float* __restrict__ h1buf) {
    int i = blockIdx.x * blockDim.x + threadIdx.x;
    if (i < H)            h0buf[i] = enc_state[i];
    else if (i < 2 * H)   h1buf[H + (i - H)] = enc_state[i];
}

// ---------------- embedding gather ----------------
__global__ void embed_kernel(const int* __restrict__ cs, const int* __restrict__ sos,
                             const int* __restrict__ tgt, const float* __restrict__ emb,
                             float* __restrict__ e_enc, float* __restrict__ e_dec) {
    int t = blockIdx.x;  // 0..127
    int id;
    float* dst;
    if (t < SEQ) { id = cs[t]; dst = e_enc + (size_t)t * EMB; }
    else         { int td = t - SEQ; id = (td == 0) ? sos[0] : tgt[td - 1]; dst = e_dec + (size_t)td * EMB; }
    const float4* src4 = (const float4*)(emb + (size_t)id * EMB);
    float4* dst4 = (float4*)dst;
    dst4[threadIdx.x] = src4[threadIdx.x];
}

// ---------------- gi0 = e @ Wih0.T + bih0 for all 64 timesteps (stays f32) ----------------
__global__ __launch_bounds__(256) void gi0_kernel(const float* __restrict__ e,
                                                  const float* __restrict__ W,
                                                  const float* __restrict__ bih,
                                                  float* __restrict__ gi) {
    int wave = (blockIdx.x * 256 + threadIdx.x) >> 6;
    int lane = threadIdx.x & 63;
    if (wave >= H3) return;
    int row = wave;
    float4 w0 = *(const float4*)(W + (size_t)row * EMB + lane * 8);
    float4 w1 = *(const float4*)(W + (size_t)row * EMB + lane * 8 + 4);
    float bb = bih[row];
    for (int t = 0; t < SEQ; ++t) {
        float4 x0 = *(const float4*)(e + (size_t)t * EMB + lane * 8);
        float4 x1 = *(const float4*)(e + (size_t)t * EMB + lane * 8 + 4);
        float s = w0.x * x0.x + w0.y * x0.y + w0.z * x0.z + w0.w * x0.w
                + w1.x * x1.x + w1.y * x1.y + w1.z * x1.z + w1.w * x1.w;
        #pragma unroll
        for (int m = 1; m < 64; m <<= 1) s += __shfl_xor(s, m);
        if (lane == 0) gi[(size_t)t * H3 + row] = s + bb;
    }
}

// ---------------- row-dot helpers (K=1024), one wave per dot ----------------
__device__ __forceinline__ float dot_f32(const float* __restrict__ wrow,
                                         const float* __restrict__ x, int lane) {
    float s = 0.f;
    #pragma unroll
    for (int i = 0; i < 4; ++i) {
        int k = lane * 4 + i * 256;
        float4 wv = *(const float4*)(wrow + k);
        float4 xv = *(const float4*)(x + k);
        s += wv.x * xv.x + wv.y * xv.y + wv.z * xv.z + wv.w * xv.w;
    }
    return s;
}
__device__ __forceinline__ float dot_bf16(const unsigned short* __restrict__ wrow,
                                          const float* __restrict__ x, int lane) {
    float s = 0.f;
    #pragma unroll
    for (int i = 0; i < 2; ++i) {
        int k = lane * 8 + i * 512;
        us8 wv = *(const us8*)(wrow + k);
        float4 x0 = *(const float4*)(x + k);
        float4 x1 = *(const float4*)(x + k + 4);
        s += bf2f(wv[0]) * x0.x + bf2f(wv[1]) * x0.y + bf2f(wv[2]) * x0.z + bf2f(wv[3]) * x0.w
           + bf2f(wv[4]) * x1.x + bf2f(wv[5]) * x1.y + bf2f(wv[6]) * x1.z + bf2f(wv[7]) * x1.w;
    }
    return s;
}

// ---------------- phase kernel: one wave = one K=1024 row-dot ----------------
// Blocks 0..511   (A): block b owns j = {2b, 2b+1} of layer0; wave w -> (t=w/3, g=w%3)
// Blocks 512..1535(B): block owns j = b-512 of layer1; waves 0-2 ih gates, 3-5 hh gates
template<int BF>
__global__ __launch_bounds__(384) void phase_kernel(
    const float* __restrict__ giA, const void* __restrict__ WhhA, const float* __restrict__ bhhA,
    const float* __restrict__ h0r, float* __restrict__ h0w, float* __restrict__ statesA, int hasA,
    const void* __restrict__ WihB, const float* __restrict__ bihB,
    const void* __restrict__ WhhB, const float* __restrict__ bhhB,
    const float* __restrict__ h1r, float* __restrict__ h1w, float* __restrict__ statesB, int hasB) {
    __shared__ float sred[8];
    int bid = blockIdx.x;
    int tid = threadIdx.x;
    int w = tid >> 6, lane = tid & 63;
    if (bid < 512) {
        if (!hasA) return;
        int tt = w / 3, g = w - tt * 3;
        int j = bid * 2 + tt;
        size_t roff = (size_t)(g * H + j) * H;
        float s = BF ? dot_bf16((const unsigned short*)WhhA + roff, h0r, lane)
                     : dot_f32((const float*)WhhA + roff, h0r, lane);
        #pragma unroll
        for (int m = 1; m < 64; m <<= 1) s += __shfl_xor(s, m);
        if (lane == 0) sred[w] = s;
        __syncthreads();
        if (tid < 2) {
            int jj = bid * 2 + tid;
            float s0 = sred[tid * 3], s1 = sred[tid * 3 + 1], s2 = sred[tid * 3 + 2];
            float r = sigmoidf_(giA[jj] + s0 + bhhA[jj]);
            float z = sigmoidf_(giA[H + jj] + s1 + bhhA[H + jj]);
            float n = tanhf(giA[2 * H + jj] + r * (s2 + bhhA[2 * H + jj]));
            float hn = (1.f - z) * n + z * h0r[jj];
            h0w[jj] = hn;
            if (statesA) statesA[jj] = hn;
        }
    } else {
        if (!hasB) return;
        int j = bid - 512;
        int hh = (w >= 3);
        int g = w - hh * 3;
        size_t roff = (size_t)(g * H + j) * H;
        const void* Wp = hh ? WhhB : WihB;
        const float* x = hh ? h1r : h0r;
        float s = BF ? dot_bf16((const unsigned short*)Wp + roff, x, lane)
                     : dot_f32((const float*)Wp + roff, x, lane);
        #pragma unroll
        for (int m = 1; m < 64; m <<= 1) s += __shfl_xor(s, m);
        if (lane == 0) sred[w] = s;
        __syncthreads();
        if (tid == 0) {
            float r = sigmoidf_(sred[0] + bihB[j] + sred[3] + bhhB[j]);
            float z = sigmoidf_(sred[1] + bihB[H + j] + sred[4] + bhhB[H + j]);
            float n = tanhf(sred[2] + bihB[2 * H + j] + r * (sred[5] + bhhB[2 * H + j]));
            float hn = (1.f - z) * n + z * h1r[j];
            h1w[j] = hn;
            if (statesB) statesB[j] = hn;
        }
    }
}

// ---------------- scores GEMM, split-K ----------------
#define SN 64
#define SK 64
template<int BF>
__global__ __launch_bounds__(256) void scores_kernel(const float* __restrict__ states,
                                                     const void* __restrict__ W,
                                                     const float* __restrict__ bias,
                                                     float* __restrict__ dst, int kc_count) {
    __shared__ float As[SK][64 + 1];
    __shared__ float Bs[SK][SN + 1];
    int n0 = blockIdx.x * SN;
    int kc = blockIdx.y;
    int klen = H / kc_count;
    int kbeg = kc * klen;
    int tid = threadIdx.x;
    int tn = tid & 15, tm = tid >> 4;
    float acc[4][4] = {};
    for (int k0 = kbeg; k0 < kbeg + klen; k0 += SK) {
        for (int i = tid; i < 64 * (SK / 4); i += 256) {
            int m = i >> 4;
            int kq = i & 15;
            float4 v = *(const float4*)(states + (size_t)m * 2048 + H + k0 + kq * 4);
            As[kq * 4 + 0][m] = v.x; As[kq * 4 + 1][m] = v.y;
            As[kq * 4 + 2][m] = v.z; As[kq * 4 + 3][m] = v.w;
        }
        if (BF) {
            for (int i = tid; i < SN * (SK / 8); i += 256) {
                int n = i >> 3;
                int ko = (i & 7) * 8;
                int r = n0 + n;
                if (r < V) {
                    us8 v = *(const us8*)((const unsigned short*)W + (size_t)r * H + k0 + ko);
                    #pragma unroll
                    for (int d = 0; d < 8; ++d) Bs[ko + d][n] = bf2f(v[d]);
                } else {
                    #pragma unroll
                    for (int d = 0; d < 8; ++d) Bs[ko + d][n] = 0.f;
                }
            }
        } else {
            for (int i = tid; i < SN * (SK / 4); i += 256) {
                int n = i >> 4;
                int kq = i & 15;
                int r = n0 + n;
                float4 v = make_float4(0.f, 0.f, 0.f, 0.f);
                if (r < V) v = *(const float4*)((const float*)W + (size_t)r * H + k0 + kq * 4);
                Bs[kq * 4 + 0][n] = v.x; Bs[kq * 4 + 1][n] = v.y;
                Bs[kq * 4 + 2][n] = v.z; Bs[kq * 4 + 3][n] = v.w;
            }
        }
        __syncthreads();
        #pragma unroll 8
        for (int k = 0; k < SK; ++k) {
            float a[4], b[4];
            #pragma unroll
            for (int i = 0; i < 4; ++i) a[i] = As[k][tm * 4 + i];
            #pragma unroll
            for (int j = 0; j < 4; ++j) b[j] = Bs[k][tn * 4 + j];
            #pragma unroll
            for (int i = 0; i < 4; ++i)
                #pragma unroll
                for (int j = 0; j < 4; ++j) acc[i][j] += a[i] * b[j];
        }
        __syncthreads();
    }
    if (kc_count == 1) {
        #pragma unroll
        for (int i = 0; i < 4; ++i) {
            int m = tm * 4 + i;
            #pragma unroll
            for (int j = 0; j < 4; ++j) {
                int r = n0 + tn * 4 + j;
                if (r < V) dst[(size_t)m * V + r] = acc[i][j] + bias[r];
            }
        }
    } else {
        #pragma unroll
        for (int i = 0; i < 4; ++i) {
            int m = tm * 4 + i;
            #pragma unroll
            for (int j = 0; j < 4; ++j) {
                int r = n0 + tn * 4 + j;
                dst[(size_t)(kc * 64 + m) * NPAD + r] = acc[i][j];
            }
        }
    }
}

__global__ __launch_bounds__(256) void reduce_scores_kernel(const float* __restrict__ part,
                                                            const float* __restrict__ bias,
                                                            float* __restrict__ out, int kc_count) {
    int e = blockIdx.x * 256 + threadIdx.x;
    if (e >= 64 * V) return;
    int m = e / V, r = e - m * V;
    float s = bias[r];
    for (int kc = 0; kc < kc_count; ++kc)
        s += part[(size_t)(kc * 64 + m) * NPAD + r];
    out[(size_t)m * V + r] = s;
}

extern "C" void kernel_launch(void* const* d_in, const int* in_sizes, int n_in,
                              void* d_out, int out_size, void* d_ws, size_t ws_size,
                              hipStream_t stream) {
    const int*   char_seq  = (const int*)d_in[0];
    const float* enc_state = (const float*)d_in[1];
    const int*   sos       = (const int*)d_in[2];
    const int*   tgt       = (const int*)d_in[5];
    const float* emb       = (const float*)d_in[6];
    const float* enc_Wih0  = (const float*)d_in[7];
    const float* enc_Whh0  = (const float*)d_in[8];
    const float* enc_bih0  = (const float*)d_in[9];
    const float* enc_bhh0  = (const float*)d_in[10];
    const float* enc_Wih1  = (const float*)d_in[11];
    const float* enc_Whh1  = (const float*)d_in[12];
    const float* enc_bih1  = (const float*)d_in[13];
    const float* enc_bhh1  = (const float*)d_in[14];
    const float* dec_Wih0  = (const float*)d_in[15];
    const float* dec_Whh0  = (const float*)d_in[16];
    const float* dec_bih0  = (const float*)d_in[17];
    const float* dec_bhh0  = (const float*)d_in[18];
    const float* dec_Wih1  = (const float*)d_in[19];
    const float* dec_Whh1  = (const float*)d_in[20];
    const float* dec_bih1  = (const float*)d_in[21];
    const float* dec_bhh1  = (const float*)d_in[22];
    const float* out_W     = (const float*)d_in[23];
    const float* out_b     = (const float*)d_in[24];

    float* ws = (float*)d_ws;
    float* e_enc   = ws;                       // 64*512
    float* e_dec   = e_enc + SEQ * EMB;        // 64*512
    float* gi_enc0 = e_dec + SEQ * EMB;        // 64*3072
    float* gi_dec0 = gi_enc0 + SEQ * H3;       // 64*3072
    float* h0buf   = gi_dec0 + SEQ * H3;       // 2*1024
    float* h1buf   = h0buf + 2 * H;            // 2*1024
    float* cur     = h1buf + 2 * H;
    size_t base = (size_t)(cur - ws);
    size_t avail = ws_size / 4 > base ? ws_size / 4 - base : 0;

    const size_t REC_ELEMS = (size_t)H3 * H;          // 3,145,728 per matrix
    const size_t REC_SLOTS = REC_ELEMS / 2;           // float-slots per bf16 matrix
    const size_t OUT_ELEMS = (size_t)V * H;           // 10,240,000
    const size_t OUT_SLOTS = OUT_ELEMS / 2;

    // feature selection, deterministic from ws_size
    int bf_rec = (avail >= 6 * REC_SLOTS);
    unsigned short* wbf[6] = {};
    if (bf_rec) {
        for (int m = 0; m < 6; ++m) { wbf[m] = (unsigned short*)cur; cur += REC_SLOTS; }
        avail -= 6 * REC_SLOTS;
    }
    int bf_out = (avail >= OUT_SLOTS);
    unsigned short* owbf = nullptr;
    if (bf_out) { owbf = (unsigned short*)cur; cur += OUT_SLOTS; avail -= OUT_SLOTS; }
    const size_t P4 = (size_t)4 * 64 * NPAD, P2 = (size_t)2 * 64 * NPAD;
    int KC = (avail >= P4) ? 4 : (avail >= P2) ? 2 : 1;
    float* partials = cur;

    float* scores = (float*)d_out;             // 64*10000
    float* states = scores + SEQ * V;          // 64*2048

    // ---- weight conversion (one-time per call) ----
    if (bf_rec) {
        const float* srcs[6] = { enc_Whh0, enc_Wih1, enc_Whh1, dec_Whh0, dec_Wih1, dec_Whh1 };
        for (int m = 0; m < 6; ++m)
            f2bf_kernel<<<(int)(REC_ELEMS / 2048), 256, 0, stream>>>(srcs[m], wbf[m], (int)REC_ELEMS);
    }
    if (bf_out)
        f2bf_kernel<<<(int)(OUT_ELEMS / 2048), 256, 0, stream>>>(out_W, owbf, (int)OUT_ELEMS);

    init_h_kernel<<<8, 256, 0, stream>>>(enc_state, h0buf, h1buf);
    embed_kernel<<<128, 128, 0, stream>>>(char_seq, sos, tgt, emb, e_enc, e_dec);
    gi0_kernel<<<H3 / 4, 256, 0, stream>>>(e_enc, enc_Wih0, enc_bih0, gi_enc0);
    gi0_kernel<<<H3 / 4, 256, 0, stream>>>(e_dec, dec_Wih0, dec_bih0, gi_dec0);

    for (int p = 0; p <= 128; ++p) {
        int hasA = (p <= 127);
        int hasB = (p >= 1);
        const float* giA = nullptr; const void* WhhA = nullptr; const float* bhhA = nullptr;
        float* statesA = nullptr;
        if (hasA) {
            if (p < 64) {
                giA = gi_enc0 + (size_t)p * H3; bhhA = enc_bhh0;
                WhhA = bf_rec ? (const void*)wbf[0] : (const void*)enc_Whh0;
            } else {
                int t = p - 64;
                giA = gi_dec0 + (size_t)t * H3; bhhA = dec_bhh0;
                WhhA = bf_rec ? (const void*)wbf[3] : (const void*)dec_Whh0;
                statesA = states + (size_t)t * 2048;
            }
        }
        const void *WihB = nullptr, *WhhB = nullptr;
        const float *bihB = nullptr, *bhhB = nullptr;
        float* statesB = nullptr;
        if (hasB) {
            if (p <= 64) {
                bihB = enc_bih1; bhhB = enc_bhh1;
                WihB = bf_rec ? (const void*)wbf[1] : (const void*)enc_Wih1;
                WhhB = bf_rec ? (const void*)wbf[2] : (const void*)enc_Whh1;
            } else {
                int t = p - 65;
                bihB = dec_bih1; bhhB = dec_bhh1;
                WihB = bf_rec ? (const void*)wbf[4] : (const void*)dec_Wih1;
                WhhB = bf_rec ? (const void*)wbf[5] : (const void*)dec_Whh1;
                statesB = states + (size_t)t * 2048 + H;
            }
        }
        float* h0r = h0buf + (p & 1) * H;
        float* h0w = h0buf + ((p + 1) & 1) * H;
        float* h1r = h1buf + (p & 1) * H;
        float* h1w = h1buf + ((p + 1) & 1) * H;
        if (bf_rec)
            phase_kernel<1><<<1536, 384, 0, stream>>>(giA, WhhA, bhhA, h0r, h0w, statesA, hasA,
                                                      WihB, bihB, WhhB, bhhB, h1r, h1w, statesB, hasB);
        else
            phase_kernel<0><<<1536, 384, 0, stream>>>(giA, WhhA, bhhA, h0r, h0w, statesA, hasA,
                                                      WihB, bihB, WhhB, bhhB, h1r, h1w, statesB, hasB);
    }

    const void* Wsc = bf_out ? (const void*)owbf : (const void*)out_W;
    if (KC == 1) {
        if (bf_out)
            scores_kernel<1><<<dim3((V + SN - 1) / SN, 1), 256, 0, stream>>>(states, Wsc, out_b, scores, 1);
        else
            scores_kernel<0><<<dim3((V + SN - 1) / SN, 1), 256, 0, stream>>>(states, Wsc, out_b, scores, 1);
    } else {
        if (bf_out)
            scores_kernel<1><<<dim3((V + SN - 1) / SN, KC), 256, 0, stream>>>(states, Wsc, out_b, partials, KC);
        else
            scores_kernel<0><<<dim3((V + SN - 1) / SN, KC), 256, 0, stream>>>(states, Wsc, out_b, partials, KC);
        reduce_scores_kernel<<<(64 * V + 255) / 256, 256, 0, stream>>>(partials, out_b, scores, KC);
    }
}